// Round 9
// baseline (96.641 us; speedup 1.0000x reference)
//
#include <hip/hip_runtime.h>
#include <hip/hip_cooperative_groups.h>

namespace cg = cooperative_groups;

#define BATCH    8
#define T_LEN    4096
#define D_DIM    128
#define H_HEADS  4
#define O_DIM    32
#define E_EDGES  65536
#define N_NODES  (BATCH * T_LEN)      // 32768
#define NEG_SLOPE 0.2f
#define ELLCAP   64                   // slots per node (mean deg 16, sd 4)
#define SPILLCAP 8192

// ---------------------------------------------------------------------------
// Inline int64-vs-int32 layout detection (edge values < 4096, so int64 data
// has every odd 32-bit word zero). Done by wave 0 of each block.
// ---------------------------------------------------------------------------
__device__ __forceinline__ int detect_shift(const int* ei, int tidx, int* s_sh) {
    if (tidx < 64) {
        const int nz = (ei[2 * tidx + 1] != 0) ? 1 : 0;
        const unsigned long long b = __ballot(nz);
        if (tidx == 0) *s_sh = (b == 0ull) ? 1 : 0;
    }
    __syncthreads();
    return *s_sh;
}

// ---------------------------------------------------------------------------
// Cooperative fused kernel, 256 blocks x 256 threads (1 block/CU, 135 KB LDS,
// co-residency guaranteed):
//   phase 0: zero cnt + spill_cnt (grid-strided)
//   grid.sync()
//   phase 1: ELL build (1 edge/thread, atomics; hides under GEMM staging)
//          + GEMM h=X*W with 4x16 register blocking + fused attention logits
// XCD-swizzled: blk%8 = batch, so the XCD that writes batch b's h/aS slab is
// the one that reads it in gather.
// ---------------------------------------------------------------------------
__launch_bounds__(256)
__global__ void fused_kernel(const float* __restrict__ x,
                             const float* __restrict__ W,
                             const float* __restrict__ attS,
                             const float* __restrict__ attD,
                             const int* __restrict__ ei,
                             float* __restrict__ h,
                             float* __restrict__ aS,
                             float* __restrict__ aD,
                             int* __restrict__ cnt,
                             int* __restrict__ ell,
                             int* __restrict__ spill_cnt,
                             int2* __restrict__ spill) {
    __shared__ float Wl[128][132];
    __shared__ float Xl[128][132];
    __shared__ float sAS[128];
    __shared__ float sAD[128];
    __shared__ int   s_sh;

    const int tid = threadIdx.x;
    const int blk = blockIdx.x;

    // ---- phase 0: zero cnt[4096] + spill_cnt (4097 ints)
    const int gid = blk * 256 + tid;
    if (gid < T_LEN + 1) cnt[gid] = 0;

    cg::this_grid().sync();

    // ---- phase 1a: ELL build — 1 edge per thread (exactly covers E_EDGES)
    const int sh = detect_shift(ei, tid, &s_sh);
    {
        const int s = ei[gid << sh];
        const int d = ei[(E_EDGES + gid) << sh];
        const int p = atomicAdd(&cnt[d], 1);
        if (p < ELLCAP) {
            ell[d * ELLCAP + p] = s;
        } else {
            const int q = atomicAdd(spill_cnt, 1);
            if (q < SPILLCAP) spill[q] = make_int2(s, d);
        }
    }

    // ---- phase 1b: GEMM (identical math to R7/R8, verified)
    // batch = blk%8 (XCD pin), tile = blk/8
    const int row0 = (blk & 7) * T_LEN + ((blk >> 3) << 7);

    const float4* W4 = (const float4*)W;
    const float4* X4 = (const float4*)(x + (size_t)row0 * 128);
    #pragma unroll
    for (int i = 0; i < 16; ++i) {
        const int idx = tid + 256 * i;
        const int row = idx >> 5;
        const int c4  = idx & 31;
        *(float4*)&Wl[row][c4 * 4] = W4[idx];
        *(float4*)&Xl[row][c4 * 4] = X4[idx];
    }
    if (tid < 128) { sAS[tid] = attS[tid]; sAD[tid] = attD[tid]; }
    __syncthreads();

    const int cb = tid & 7;      // col group
    const int rg = tid >> 3;     // row group 0..31
    const int c0 = cb * 4;       // first col of chunk i is c0 + 32*i

    float4 acc[4][4];            // [ri][i]
    #pragma unroll
    for (int a = 0; a < 4; ++a)
        #pragma unroll
        for (int b = 0; b < 4; ++b)
            acc[a][b] = make_float4(0.f, 0.f, 0.f, 0.f);

    for (int k = 0; k < 128; ++k) {
        float xv[4];
        #pragma unroll
        for (int ri = 0; ri < 4; ++ri) xv[ri] = Xl[rg + 32 * ri][k];
        float4 wv[4];
        #pragma unroll
        for (int i = 0; i < 4; ++i) wv[i] = *(const float4*)&Wl[k][c0 + 32 * i];
        #pragma unroll
        for (int ri = 0; ri < 4; ++ri) {
            #pragma unroll
            for (int i = 0; i < 4; ++i) {
                acc[ri][i].x += xv[ri] * wv[i].x;
                acc[ri][i].y += xv[ri] * wv[i].y;
                acc[ri][i].z += xv[ri] * wv[i].z;
                acc[ri][i].w += xv[ri] * wv[i].w;
            }
        }
    }

    #pragma unroll
    for (int ri = 0; ri < 4; ++ri) {
        const int row = row0 + rg + 32 * ri;
        #pragma unroll
        for (int i = 0; i < 4; ++i)
            *(float4*)&h[(size_t)row * 128 + c0 + 32 * i] = acc[ri][i];

        float4 ps = make_float4(0.f, 0.f, 0.f, 0.f);
        float4 pd = make_float4(0.f, 0.f, 0.f, 0.f);
        #pragma unroll
        for (int i = 0; i < 4; ++i) {
            const float* as = &sAS[32 * i + c0];
            const float* ad = &sAD[32 * i + c0];
            float s_ = acc[ri][i].x * as[0] + acc[ri][i].y * as[1]
                     + acc[ri][i].z * as[2] + acc[ri][i].w * as[3];
            float d_ = acc[ri][i].x * ad[0] + acc[ri][i].y * ad[1]
                     + acc[ri][i].z * ad[2] + acc[ri][i].w * ad[3];
            if (i == 0) { ps.x = s_; pd.x = d_; }
            if (i == 1) { ps.y = s_; pd.y = d_; }
            if (i == 2) { ps.z = s_; pd.z = d_; }
            if (i == 3) { ps.w = s_; pd.w = d_; }
        }
        #pragma unroll
        for (int off = 1; off < 8; off <<= 1) {
            ps.x += __shfl_xor(ps.x, off); ps.y += __shfl_xor(ps.y, off);
            ps.z += __shfl_xor(ps.z, off); ps.w += __shfl_xor(ps.w, off);
            pd.x += __shfl_xor(pd.x, off); pd.y += __shfl_xor(pd.y, off);
            pd.z += __shfl_xor(pd.z, off); pd.w += __shfl_xor(pd.w, off);
        }
        if (cb == 0) {
            *(float4*)&aS[(size_t)row * 4] = ps;
            *(float4*)&aD[(size_t)row * 4] = pd;
        }
    }
}

// ---------------------------------------------------------------------------
// Gather-aggregate (unchanged from R8, verified): wave = one (batch,node).
// Phase 1: stage ELL col + w4 = exp(lrelu(aS4[s]+aD4[n])) into LDS.
// Phase 2: dependence-free channel loop. Zero atomics, spill fallback.
// ---------------------------------------------------------------------------
__launch_bounds__(256)
__global__ void gather_kernel(const int* __restrict__ cnt,
                              const int* __restrict__ ell,
                              const int* __restrict__ spill_cnt,
                              const int2* __restrict__ spill,
                              const float* __restrict__ h,
                              const float* __restrict__ aS,
                              const float* __restrict__ aD,
                              const float* __restrict__ bias,
                              float* __restrict__ out) {
    __shared__ int   sbuf[4][ELLCAP + 1];
    __shared__ float wbuf[4][ELLCAP + 1][4];

    const int batch = blockIdx.x & 7;                 // XCD pin: batch slab in L2
    const int wv    = threadIdx.x >> 6;               // wave 0..3
    const int nib   = ((blockIdx.x >> 3) << 2) + wv;  // node within batch
    const int lane  = threadIdx.x & 63;
    const int base  = batch * T_LEN;
    const int n     = base + nib;
    const int hh    = lane >> 4;                      // head of channels 2*lane

    const int deg = cnt[nib];
    const int m   = (deg < ELLCAP) ? deg : ELLCAP;    // staged edge count

    const float4 ad4 = *(const float4*)(aD + (size_t)n * 4);

    // ---- phase 1: stage edges (lane j -> slot j)
    if (lane < m) {
        const int s = ell[nib * ELLCAP + lane] + base;
        const float4 as4 = *(const float4*)(aS + (size_t)s * 4);
        float4 l;
        l.x = as4.x + ad4.x; l.x = (l.x > 0.f) ? l.x : NEG_SLOPE * l.x;
        l.y = as4.y + ad4.y; l.y = (l.y > 0.f) ? l.y : NEG_SLOPE * l.y;
        l.z = as4.z + ad4.z; l.z = (l.z > 0.f) ? l.z : NEG_SLOPE * l.z;
        l.w = as4.w + ad4.w; l.w = (l.w > 0.f) ? l.w : NEG_SLOPE * l.w;
        sbuf[wv][lane]    = s;
        wbuf[wv][lane][0] = __expf(l.x);
        wbuf[wv][lane][1] = __expf(l.y);
        wbuf[wv][lane][2] = __expf(l.z);
        wbuf[wv][lane][3] = __expf(l.w);
    }
    // self loop -> slot m (lane m for m<64; lane 0 doubles up when m==64)
    if (lane == (m & 63)) {
        const float4 as4 = *(const float4*)(aS + (size_t)n * 4);
        float4 l;
        l.x = as4.x + ad4.x; l.x = (l.x > 0.f) ? l.x : NEG_SLOPE * l.x;
        l.y = as4.y + ad4.y; l.y = (l.y > 0.f) ? l.y : NEG_SLOPE * l.y;
        l.z = as4.z + ad4.z; l.z = (l.z > 0.f) ? l.z : NEG_SLOPE * l.z;
        l.w = as4.w + ad4.w; l.w = (l.w > 0.f) ? l.w : NEG_SLOPE * l.w;
        sbuf[wv][m]    = n;
        wbuf[wv][m][0] = __expf(l.x);
        wbuf[wv][m][1] = __expf(l.y);
        wbuf[wv][m][2] = __expf(l.z);
        wbuf[wv][m][3] = __expf(l.w);
    }
    // wave-synchronous: same wave wrote, same wave reads (DS ops in order)

    // ---- phase 2: channel accumulation (no dependent chain)
    float accx = 0.f, accy = 0.f, dsum = 0.f;
    const int nst = m + 1;
    #pragma unroll 4
    for (int j = 0; j < nst; ++j) {
        const int   s = sbuf[wv][j];
        const float w = wbuf[wv][j][hh];
        dsum += w;
        const float2 hv = *(const float2*)(h + (size_t)s * 128 + 2 * lane);
        accx += w * hv.x;
        accy += w * hv.y;
    }

    // ---- spill fallback (guaranteed-correct; count is 0 for this data)
    int sc = *spill_cnt;
    if (sc > 0) {
        if (sc > SPILLCAP) sc = SPILLCAP;
        const float adh = aD[(size_t)n * 4 + hh];
        for (int q = 0; q < sc; ++q) {
            const int2 e = spill[q];
            if (e.y == nib) {
                const int s = e.x + base;
                float l = aS[(size_t)s * 4 + hh] + adh;
                l = (l > 0.f) ? l : NEG_SLOPE * l;
                const float w = __expf(l);
                dsum += w;
                const float2 hv = *(const float2*)(h + (size_t)s * 128 + 2 * lane);
                accx += w * hv.x;
                accy += w * hv.y;
            }
        }
    }

    const float inv = 1.0f / (dsum + 1e-16f);
    const float2 bv = *(const float2*)(bias + 2 * lane);
    float2 o;
    o.x = accx * inv + bv.x;
    o.y = accy * inv + bv.y;
    *(float2*)(out + (size_t)n * 128 + 2 * lane) = o;
}

// ---------------------------------------------------------------------------
extern "C" void kernel_launch(void* const* d_in, const int* in_sizes, int n_in,
                              void* d_out, int out_size, void* d_ws, size_t ws_size,
                              hipStream_t stream) {
    const float* x    = (const float*)d_in[0];
    const int*   ei   = (const int*)  d_in[1];
    const float* W    = (const float*)d_in[2];
    const float* attS = (const float*)d_in[3];
    const float* attD = (const float*)d_in[4];
    const float* bias = (const float*)d_in[5];
    float* out = (float*)d_out;

    // workspace layout (4-byte units; base is 16B-aligned)
    float* ws        = (float*)d_ws;
    float* h         = ws;                                   // N*128
    float* aS        = h  + (size_t)N_NODES * 128;           // N*4
    float* aD        = aS + (size_t)N_NODES * 4;             // N*4
    int*   cnt       = (int*)(aD + (size_t)N_NODES * 4);     // T_LEN (+1 spill_cnt)
    int*   spill_cnt = cnt + T_LEN;                          // 1
    int*   ell       = spill_cnt + 2;                        // T_LEN*ELLCAP
    int2*  spill     = (int2*)(ell + T_LEN * ELLCAP);        // SPILLCAP int2

    // cooperative fused: zero -> grid.sync -> ELL build || GEMM+logits
    void* args[] = {
        (void*)&x, (void*)&W, (void*)&attS, (void*)&attD, (void*)&ei,
        (void*)&h, (void*)&aS, (void*)&aD,
        (void*)&cnt, (void*)&ell, (void*)&spill_cnt, (void*)&spill
    };
    hipLaunchCooperativeKernel((void*)fused_kernel, dim3(256), dim3(256),
                               args, 0, stream);

    // gather-aggregate with fused softmax-normalize + bias (high occupancy)
    gather_kernel<<<N_NODES / 4, 256, 0, stream>>>(cnt, ell, spill_cnt, spill,
                                                   h, aS, aD, bias, out);
}

// Round 10
// 53.610 us; speedup vs baseline: 1.8027x; 1.8027x over previous
//
#include <hip/hip_runtime.h>

#define BATCH    8
#define T_LEN    4096
#define D_DIM    128
#define H_HEADS  4
#define O_DIM    32
#define E_EDGES  65536
#define N_NODES  (BATCH * T_LEN)      // 32768
#define NEG_SLOPE 0.2f
#define ELLCAP   64
#define SPILLCAP 8192
#define GEMM_BLOCKS 512               // 64 rows each

typedef __attribute__((ext_vector_type(8))) short short8;
typedef __attribute__((ext_vector_type(4))) float f32x4;

// round-to-nearest-even fp32 -> bf16 bits
__device__ __forceinline__ unsigned int bf16b(float f) {
    unsigned int u = __float_as_uint(f);
    u += 0x7FFFu + ((u >> 16) & 1u);
    return u >> 16;
}
__device__ __forceinline__ unsigned int bf16pack(float lo, float hi) {
    return bf16b(lo) | (bf16b(hi) << 16);
}

// ---------------------------------------------------------------------------
// int64-vs-int32 layout detection (edge values < 4096 -> int64 odd words all 0)
// ---------------------------------------------------------------------------
__device__ __forceinline__ int detect_shift(const int* ei, int tidx, int* s_sh) {
    if (tidx < 64) {
        const int nz = (ei[2 * tidx + 1] != 0) ? 1 : 0;
        const unsigned long long b = __ballot(nz);
        if (tidx == 0) *s_sh = (b == 0ull) ? 1 : 0;
    }
    __syncthreads();
    return *s_sh;
}

// ---------------------------------------------------------------------------
// Fused: blocks [0,512) = bf16-MFMA GEMM h=X*W + attention logits (64 rows
// per block, 52 KB LDS -> 3 blocks/CU); blocks [512,768) = ELL build.
// MFMA fragment layout (m97-lineage, ref-checked): A[l&15][k0+(l>>4)*8+j],
// B = Wt[col l&15][same ks], D: row=(l>>4)*4+reg, col=l&15.
// ---------------------------------------------------------------------------
__launch_bounds__(256)
__global__ void gemm_ell_kernel(const float* __restrict__ x,
                                const float* __restrict__ W,
                                const float* __restrict__ attS,
                                const float* __restrict__ attD,
                                const int* __restrict__ ei,
                                float* __restrict__ h,
                                float* __restrict__ aS,
                                float* __restrict__ aD,
                                int* __restrict__ cnt,
                                int* __restrict__ ell,
                                int* __restrict__ spill_cnt,
                                int2* __restrict__ spill) {
    __shared__ short Xb[64][136];    // rows x k, bf16, stride 272 B (16B mult)
    __shared__ short Wt[128][136];   // cols x k, bf16 (W transposed)
    __shared__ int   s_sh;

    const int tid = threadIdx.x;

    if (blockIdx.x >= GEMM_BLOCKS) {
        // ---------------- ELL build branch ----------------
        const int sh = detect_shift(ei, tid, &s_sh);
        const int j  = (blockIdx.x - GEMM_BLOCKS) * 256 + tid;  // covers E_EDGES
        const int s  = ei[j << sh];
        const int d  = ei[(E_EDGES + j) << sh];
        const int p  = atomicAdd(&cnt[d], 1);
        if (p < ELLCAP) {
            ell[d * ELLCAP + p] = s;
        } else {
            const int q = atomicAdd(spill_cnt, 1);
            if (q < SPILLCAP) spill[q] = make_int2(s, d);
        }
        return;
    }

    // ---------------- GEMM branch ----------------
    // batch = blk%8 (XCD pin), 64-row tile = blk/8
    const int row0 = (blockIdx.x & 7) * T_LEN + ((blockIdx.x >> 3) << 6);

    // stage X tile (64x128 fp32 -> bf16), coalesced float4 reads
    const float4* X4 = (const float4*)(x + (size_t)row0 * 128);
    #pragma unroll
    for (int i = 0; i < 8; ++i) {
        const int idx = tid + 256 * i;
        const int row = idx >> 5;
        const int c4  = (idx & 31) * 4;
        const float4 v = X4[idx];
        uint2 u;
        u.x = bf16pack(v.x, v.y);
        u.y = bf16pack(v.z, v.w);
        *(uint2*)&Xb[row][c4] = u;
    }

    // stage W transposed (k-major -> col-major), 2 threads per col
    {
        const int c  = tid >> 1;
        const int kh = (tid & 1) * 64;
        for (int i = 0; i < 64; i += 4) {
            const float w0 = W[(size_t)(kh + i    ) * 128 + c];
            const float w1 = W[(size_t)(kh + i + 1) * 128 + c];
            const float w2 = W[(size_t)(kh + i + 2) * 128 + c];
            const float w3 = W[(size_t)(kh + i + 3) * 128 + c];
            uint2 u;
            u.x = bf16pack(w0, w1);
            u.y = bf16pack(w2, w3);
            *(uint2*)&Wt[c][kh + i] = u;
        }
    }
    __syncthreads();

    const int wv    = tid >> 6;        // wave 0..3 -> rows wv*16..+16
    const int l     = tid & 63;
    const int lr    = l & 15;
    const int lg    = l >> 4;
    const int wrow0 = wv * 16;

    f32x4 acc[8];
    #pragma unroll
    for (int cf = 0; cf < 8; ++cf) acc[cf] = (f32x4){0.f, 0.f, 0.f, 0.f};

    #pragma unroll
    for (int kt = 0; kt < 4; ++kt) {
        const int k0 = kt * 32 + lg * 8;
        const short8 a = *(const short8*)&Xb[wrow0 + lr][k0];
        #pragma unroll
        for (int cf = 0; cf < 8; ++cf) {
            const short8 b = *(const short8*)&Wt[cf * 16 + lr][k0];
            acc[cf] = __builtin_amdgcn_mfma_f32_16x16x32_bf16(a, b, acc[cf], 0, 0, 0);
        }
    }

    // store h: D row = (lg*4 + r), col = cf*16 + lr
    #pragma unroll
    for (int cf = 0; cf < 8; ++cf) {
        #pragma unroll
        for (int r = 0; r < 4; ++r) {
            const int row = row0 + wrow0 + lg * 4 + r;
            h[(size_t)row * 128 + cf * 16 + lr] = acc[cf][r];
        }
    }

    // fused attention logits: aS[n][hd] = sum_c h[n][c]*attS[c], head = c>>5
    float psr[4][4];   // [r][head]
    float pdr[4][4];
    #pragma unroll
    for (int r = 0; r < 4; ++r)
        #pragma unroll
        for (int hd = 0; hd < 4; ++hd) { psr[r][hd] = 0.f; pdr[r][hd] = 0.f; }

    #pragma unroll
    for (int cf = 0; cf < 8; ++cf) {
        const float aSc = attS[cf * 16 + lr];
        const float aDc = attD[cf * 16 + lr];
        const int   hd  = cf >> 1;
        #pragma unroll
        for (int r = 0; r < 4; ++r) {
            psr[r][hd] += acc[cf][r] * aSc;
            pdr[r][hd] += acc[cf][r] * aDc;
        }
    }
    #pragma unroll
    for (int r = 0; r < 4; ++r)
        #pragma unroll
        for (int hd = 0; hd < 4; ++hd)
            #pragma unroll
            for (int off = 1; off < 16; off <<= 1) {
                psr[r][hd] += __shfl_xor(psr[r][hd], off);
                pdr[r][hd] += __shfl_xor(pdr[r][hd], off);
            }
    if (lr == 0) {
        #pragma unroll
        for (int r = 0; r < 4; ++r) {
            const int row = row0 + wrow0 + lg * 4 + r;
            *(float4*)&aS[(size_t)row * 4] =
                make_float4(psr[r][0], psr[r][1], psr[r][2], psr[r][3]);
            *(float4*)&aD[(size_t)row * 4] =
                make_float4(pdr[r][0], pdr[r][1], pdr[r][2], pdr[r][3]);
        }
    }
}

// ---------------------------------------------------------------------------
// Gather-aggregate (unchanged from R8, verified): wave = one (batch,node).
// Phase 1: stage ELL col + w4 = exp(lrelu(aS4[s]+aD4[n])) into LDS.
// Phase 2: dependence-free channel loop. Zero atomics, spill fallback.
// ---------------------------------------------------------------------------
__launch_bounds__(256)
__global__ void gather_kernel(const int* __restrict__ cnt,
                              const int* __restrict__ ell,
                              const int* __restrict__ spill_cnt,
                              const int2* __restrict__ spill,
                              const float* __restrict__ h,
                              const float* __restrict__ aS,
                              const float* __restrict__ aD,
                              const float* __restrict__ bias,
                              float* __restrict__ out) {
    __shared__ int   sbuf[4][ELLCAP + 1];
    __shared__ float wbuf[4][ELLCAP + 1][4];

    const int batch = blockIdx.x & 7;                 // XCD pin: batch slab in L2
    const int wv    = threadIdx.x >> 6;               // wave 0..3
    const int nib   = ((blockIdx.x >> 3) << 2) + wv;  // node within batch
    const int lane  = threadIdx.x & 63;
    const int base  = batch * T_LEN;
    const int n     = base + nib;
    const int hh    = lane >> 4;                      // head of channels 2*lane

    const int deg = cnt[nib];
    const int m   = (deg < ELLCAP) ? deg : ELLCAP;    // staged edge count

    const float4 ad4 = *(const float4*)(aD + (size_t)n * 4);

    // ---- phase 1: stage edges (lane j -> slot j)
    if (lane < m) {
        const int s = ell[nib * ELLCAP + lane] + base;
        const float4 as4 = *(const float4*)(aS + (size_t)s * 4);
        float4 l;
        l.x = as4.x + ad4.x; l.x = (l.x > 0.f) ? l.x : NEG_SLOPE * l.x;
        l.y = as4.y + ad4.y; l.y = (l.y > 0.f) ? l.y : NEG_SLOPE * l.y;
        l.z = as4.z + ad4.z; l.z = (l.z > 0.f) ? l.z : NEG_SLOPE * l.z;
        l.w = as4.w + ad4.w; l.w = (l.w > 0.f) ? l.w : NEG_SLOPE * l.w;
        sbuf[wv][lane]    = s;
        wbuf[wv][lane][0] = __expf(l.x);
        wbuf[wv][lane][1] = __expf(l.y);
        wbuf[wv][lane][2] = __expf(l.z);
        wbuf[wv][lane][3] = __expf(l.w);
    }
    // self loop -> slot m (lane m for m<64; lane 0 doubles up when m==64)
    if (lane == (m & 63)) {
        const float4 as4 = *(const float4*)(aS + (size_t)n * 4);
        float4 l;
        l.x = as4.x + ad4.x; l.x = (l.x > 0.f) ? l.x : NEG_SLOPE * l.x;
        l.y = as4.y + ad4.y; l.y = (l.y > 0.f) ? l.y : NEG_SLOPE * l.y;
        l.z = as4.z + ad4.z; l.z = (l.z > 0.f) ? l.z : NEG_SLOPE * l.z;
        l.w = as4.w + ad4.w; l.w = (l.w > 0.f) ? l.w : NEG_SLOPE * l.w;
        sbuf[wv][m]    = n;
        wbuf[wv][m][0] = __expf(l.x);
        wbuf[wv][m][1] = __expf(l.y);
        wbuf[wv][m][2] = __expf(l.z);
        wbuf[wv][m][3] = __expf(l.w);
    }
    // wave-synchronous: same wave wrote, same wave reads

    // ---- phase 2: channel accumulation (no dependent chain)
    float accx = 0.f, accy = 0.f, dsum = 0.f;
    const int nst = m + 1;
    #pragma unroll 4
    for (int j = 0; j < nst; ++j) {
        const int   s = sbuf[wv][j];
        const float w = wbuf[wv][j][hh];
        dsum += w;
        const float2 hv = *(const float2*)(h + (size_t)s * 128 + 2 * lane);
        accx += w * hv.x;
        accy += w * hv.y;
    }

    // ---- spill fallback (count is 0 for this data; correctness guard)
    int sc = *spill_cnt;
    if (sc > 0) {
        if (sc > SPILLCAP) sc = SPILLCAP;
        const float adh = aD[(size_t)n * 4 + hh];
        for (int q = 0; q < sc; ++q) {
            const int2 e = spill[q];
            if (e.y == nib) {
                const int s = e.x + base;
                float l = aS[(size_t)s * 4 + hh] + adh;
                l = (l > 0.f) ? l : NEG_SLOPE * l;
                const float w = __expf(l);
                dsum += w;
                const float2 hv = *(const float2*)(h + (size_t)s * 128 + 2 * lane);
                accx += w * hv.x;
                accy += w * hv.y;
            }
        }
    }

    const float inv = 1.0f / (dsum + 1e-16f);
    const float2 bv = *(const float2*)(bias + 2 * lane);
    float2 o;
    o.x = accx * inv + bv.x;
    o.y = accy * inv + bv.y;
    *(float2*)(out + (size_t)n * 128 + 2 * lane) = o;
}

// ---------------------------------------------------------------------------
extern "C" void kernel_launch(void* const* d_in, const int* in_sizes, int n_in,
                              void* d_out, int out_size, void* d_ws, size_t ws_size,
                              hipStream_t stream) {
    const float* x    = (const float*)d_in[0];
    const int*   ei   = (const int*)  d_in[1];
    const float* W    = (const float*)d_in[2];
    const float* attS = (const float*)d_in[3];
    const float* attD = (const float*)d_in[4];
    const float* bias = (const float*)d_in[5];
    float* out = (float*)d_out;

    // workspace layout (4-byte units; base is 16B-aligned)
    float* ws        = (float*)d_ws;
    float* h         = ws;                                   // N*128
    float* aS        = h  + (size_t)N_NODES * 128;           // N*4
    float* aD        = aS + (size_t)N_NODES * 4;             // N*4
    int*   cnt       = (int*)(aD + (size_t)N_NODES * 4);     // T_LEN
    int*   spill_cnt = cnt + T_LEN;                          // 1
    int*   ell       = spill_cnt + 2;                        // T_LEN*ELLCAP
    int2*  spill     = (int2*)(ell + T_LEN * ELLCAP);        // SPILLCAP int2

    hipMemsetAsync(cnt, 0, (T_LEN + 1) * sizeof(int), stream);

    // fused: MFMA GEMM + logits (blocks 0..511) || ELL build (blocks 512..767)
    gemm_ell_kernel<<<GEMM_BLOCKS + 256, 256, 0, stream>>>(
        x, W, attS, attD, ei, h, aS, aD, cnt, ell, spill_cnt, spill);

    // gather-aggregate with fused softmax-normalize + bias
    gather_kernel<<<N_NODES / 4, 256, 0, stream>>>(cnt, ell, spill_cnt, spill,
                                                   h, aS, aD, bias, out);
}

// Round 11
// 42.761 us; speedup vs baseline: 2.2600x; 1.2537x over previous
//
#include <hip/hip_runtime.h>

#define BATCH    8
#define T_LEN    4096
#define D_DIM    128
#define H_HEADS  4
#define O_DIM    32
#define E_EDGES  65536
#define N_NODES  (BATCH * T_LEN)      // 32768
#define NEG_SLOPE 0.2f
#define ELLCAP   64
#define SPILLCAP 8192
#define GEMM_BLOCKS 512               // 64 rows each

typedef __attribute__((ext_vector_type(8))) short short8;
typedef __attribute__((ext_vector_type(4))) float f32x4;

// round-to-nearest-even fp32 -> bf16 bits
__device__ __forceinline__ unsigned int bf16b(float f) {
    unsigned int u = __float_as_uint(f);
    u += 0x7FFFu + ((u >> 16) & 1u);
    return u >> 16;
}
__device__ __forceinline__ unsigned int bf16pack(float lo, float hi) {
    return bf16b(lo) | (bf16b(hi) << 16);
}
__device__ __forceinline__ float bf16f(unsigned short u) {
    return __uint_as_float((unsigned int)u << 16);
}

// ---------------------------------------------------------------------------
// int64-vs-int32 layout detection (edge values < 4096 -> int64 odd words all 0)
// ---------------------------------------------------------------------------
__device__ __forceinline__ int detect_shift(const int* ei, int tidx, int* s_sh) {
    if (tidx < 64) {
        const int nz = (ei[2 * tidx + 1] != 0) ? 1 : 0;
        const unsigned long long b = __ballot(nz);
        if (tidx == 0) *s_sh = (b == 0ull) ? 1 : 0;
    }
    __syncthreads();
    return *s_sh;
}

// ---------------------------------------------------------------------------
// Prep: zero cnt[4096]+spill_cnt AND build global bf16 W^T (Wt[col][k]).
// Replaces the memset dispatch with useful work. 81 blocks x 256.
// ---------------------------------------------------------------------------
__launch_bounds__(256)
__global__ void prep_kernel(const float* __restrict__ W,
                            int* __restrict__ cnt,
                            unsigned short* __restrict__ WtG) {
    const int g = blockIdx.x * 256 + threadIdx.x;
    if (g < T_LEN + 1) cnt[g] = 0;                       // cnt + spill_cnt
    const int i = g - 4352;
    if (i >= 0 && i < 128 * 128) {
        const int k   = i >> 7;
        const int col = i & 127;                         // coalesced W read
        WtG[col * 128 + k] = (unsigned short)bf16b(W[k * 128 + col]);
    }
}

// ---------------------------------------------------------------------------
// Fused: blocks [0,512) = bf16-MFMA GEMM h=X*W + attention logits (64 rows
// per block, ~52 KB LDS -> 3 blocks/CU); blocks [512,768) = ELL build.
// MFMA fragment layout (m97-lineage, ref-checked): A[l&15][k0+(l>>4)*8+j],
// B = Wt[col l&15][same ks], D: row=(l>>4)*4+reg, col=l&15.
// h stored as bf16 (halves gather read traffic; written once, read ~17x).
// ---------------------------------------------------------------------------
__launch_bounds__(256)
__global__ void gemm_ell_kernel(const float* __restrict__ x,
                                const unsigned short* __restrict__ WtG,
                                const float* __restrict__ attS,
                                const float* __restrict__ attD,
                                const int* __restrict__ ei,
                                unsigned short* __restrict__ hb,
                                float* __restrict__ aS,
                                float* __restrict__ aD,
                                int* __restrict__ cnt,
                                int* __restrict__ ell,
                                int* __restrict__ spill_cnt,
                                int2* __restrict__ spill) {
    __shared__ short Xb[64][136];    // rows x k, bf16 (stride 272 B)
    __shared__ short Wt[128][136];   // cols x k, bf16
    __shared__ int   s_sh;

    const int tid = threadIdx.x;

    if (blockIdx.x >= GEMM_BLOCKS) {
        // ---------------- ELL build branch ----------------
        const int sh = detect_shift(ei, tid, &s_sh);
        const int j  = (blockIdx.x - GEMM_BLOCKS) * 256 + tid;  // covers E_EDGES
        const int s  = ei[j << sh];
        const int d  = ei[(E_EDGES + j) << sh];
        const int p  = atomicAdd(&cnt[d], 1);
        if (p < ELLCAP) {
            ell[d * ELLCAP + p] = s;
        } else {
            const int q = atomicAdd(spill_cnt, 1);
            if (q < SPILLCAP) spill[q] = make_int2(s, d);
        }
        return;
    }

    // ---------------- GEMM branch ----------------
    // batch = blk%8 (XCD pin), 64-row tile = blk/8
    const int row0 = (blockIdx.x & 7) * T_LEN + ((blockIdx.x >> 3) << 6);

    // stage X tile (64x128 fp32 -> bf16), coalesced float4 reads
    const float4* X4 = (const float4*)(x + (size_t)row0 * 128);
    #pragma unroll
    for (int i = 0; i < 8; ++i) {
        const int idx = tid + 256 * i;
        const int row = idx >> 5;
        const int c4  = (idx & 31) * 4;
        const float4 v = X4[idx];
        uint2 u;
        u.x = bf16pack(v.x, v.y);
        u.y = bf16pack(v.z, v.w);
        *(uint2*)&Xb[row][c4] = u;
    }

    // stage Wt (already bf16+transposed in global), coalesced short8 loads
    #pragma unroll
    for (int i = 0; i < 8; ++i) {
        const int idx = tid + 256 * i;          // 2048 chunks of 8 shorts
        const int row = idx >> 4;
        const int off = (idx & 15) * 8;
        *(short8*)&Wt[row][off] = *(const short8*)&WtG[row * 128 + off];
    }
    __syncthreads();

    const int wv    = tid >> 6;        // wave 0..3 -> rows wv*16..+16
    const int l     = tid & 63;
    const int lr    = l & 15;
    const int lg    = l >> 4;
    const int wrow0 = wv * 16;

    f32x4 acc[8];
    #pragma unroll
    for (int cf = 0; cf < 8; ++cf) acc[cf] = (f32x4){0.f, 0.f, 0.f, 0.f};

    #pragma unroll
    for (int kt = 0; kt < 4; ++kt) {
        const int k0 = kt * 32 + lg * 8;
        const short8 a = *(const short8*)&Xb[wrow0 + lr][k0];
        #pragma unroll
        for (int cf = 0; cf < 8; ++cf) {
            const short8 b = *(const short8*)&Wt[cf * 16 + lr][k0];
            acc[cf] = __builtin_amdgcn_mfma_f32_16x16x32_bf16(a, b, acc[cf], 0, 0, 0);
        }
    }

    // store h as bf16: D row = (lg*4 + r), col = cf*16 + lr
    #pragma unroll
    for (int cf = 0; cf < 8; ++cf) {
        #pragma unroll
        for (int r = 0; r < 4; ++r) {
            const int row = row0 + wrow0 + lg * 4 + r;
            hb[(size_t)row * 128 + cf * 16 + lr] = (unsigned short)bf16b(acc[cf][r]);
        }
    }

    // fused attention logits (fp32 acc): aS[n][hd] = sum_c h[n][c]*attS[c]
    float psr[4][4];   // [r][head]
    float pdr[4][4];
    #pragma unroll
    for (int r = 0; r < 4; ++r)
        #pragma unroll
        for (int hd = 0; hd < 4; ++hd) { psr[r][hd] = 0.f; pdr[r][hd] = 0.f; }

    #pragma unroll
    for (int cf = 0; cf < 8; ++cf) {
        const float aSc = attS[cf * 16 + lr];
        const float aDc = attD[cf * 16 + lr];
        const int   hd  = cf >> 1;
        #pragma unroll
        for (int r = 0; r < 4; ++r) {
            psr[r][hd] += acc[cf][r] * aSc;
            pdr[r][hd] += acc[cf][r] * aDc;
        }
    }
    #pragma unroll
    for (int r = 0; r < 4; ++r)
        #pragma unroll
        for (int hd = 0; hd < 4; ++hd)
            #pragma unroll
            for (int off = 1; off < 16; off <<= 1) {
                psr[r][hd] += __shfl_xor(psr[r][hd], off);
                pdr[r][hd] += __shfl_xor(pdr[r][hd], off);
            }
    if (lr == 0) {
        #pragma unroll
        for (int r = 0; r < 4; ++r) {
            const int row = row0 + wrow0 + lg * 4 + r;
            *(float4*)&aS[(size_t)row * 4] =
                make_float4(psr[r][0], psr[r][1], psr[r][2], psr[r][3]);
            *(float4*)&aD[(size_t)row * 4] =
                make_float4(pdr[r][0], pdr[r][1], pdr[r][2], pdr[r][3]);
        }
    }
}

// ---------------------------------------------------------------------------
// Gather-aggregate: wave = one (batch,node). Phase 1: stage ELL col + w4 =
// exp(lrelu(aS4[s]+aD4[n])) into LDS. Phase 2: dependence-free channel loop
// over bf16 h rows (256 B/wave per edge). Zero atomics, spill fallback.
// ---------------------------------------------------------------------------
__launch_bounds__(256)
__global__ void gather_kernel(const int* __restrict__ cnt,
                              const int* __restrict__ ell,
                              const int* __restrict__ spill_cnt,
                              const int2* __restrict__ spill,
                              const unsigned short* __restrict__ hb,
                              const float* __restrict__ aS,
                              const float* __restrict__ aD,
                              const float* __restrict__ bias,
                              float* __restrict__ out) {
    __shared__ int   sbuf[4][ELLCAP + 1];
    __shared__ float wbuf[4][ELLCAP + 1][4];

    const int batch = blockIdx.x & 7;                 // XCD pin: batch slab in L2
    const int wv    = threadIdx.x >> 6;               // wave 0..3
    const int nib   = ((blockIdx.x >> 3) << 2) + wv;  // node within batch
    const int lane  = threadIdx.x & 63;
    const int base  = batch * T_LEN;
    const int n     = base + nib;
    const int hh    = lane >> 4;                      // head of channels 2*lane

    const int deg = cnt[nib];
    const int m   = (deg < ELLCAP) ? deg : ELLCAP;    // staged edge count

    const float4 ad4 = *(const float4*)(aD + (size_t)n * 4);

    // ---- phase 1: stage edges (lane j -> slot j)
    if (lane < m) {
        const int s = ell[nib * ELLCAP + lane] + base;
        const float4 as4 = *(const float4*)(aS + (size_t)s * 4);
        float4 l;
        l.x = as4.x + ad4.x; l.x = (l.x > 0.f) ? l.x : NEG_SLOPE * l.x;
        l.y = as4.y + ad4.y; l.y = (l.y > 0.f) ? l.y : NEG_SLOPE * l.y;
        l.z = as4.z + ad4.z; l.z = (l.z > 0.f) ? l.z : NEG_SLOPE * l.z;
        l.w = as4.w + ad4.w; l.w = (l.w > 0.f) ? l.w : NEG_SLOPE * l.w;
        sbuf[wv][lane]    = s;
        wbuf[wv][lane][0] = __expf(l.x);
        wbuf[wv][lane][1] = __expf(l.y);
        wbuf[wv][lane][2] = __expf(l.z);
        wbuf[wv][lane][3] = __expf(l.w);
    }
    // self loop -> slot m (lane m for m<64; lane 0 doubles up when m==64)
    if (lane == (m & 63)) {
        const float4 as4 = *(const float4*)(aS + (size_t)n * 4);
        float4 l;
        l.x = as4.x + ad4.x; l.x = (l.x > 0.f) ? l.x : NEG_SLOPE * l.x;
        l.y = as4.y + ad4.y; l.y = (l.y > 0.f) ? l.y : NEG_SLOPE * l.y;
        l.z = as4.z + ad4.z; l.z = (l.z > 0.f) ? l.z : NEG_SLOPE * l.z;
        l.w = as4.w + ad4.w; l.w = (l.w > 0.f) ? l.w : NEG_SLOPE * l.w;
        sbuf[wv][m]    = n;
        wbuf[wv][m][0] = __expf(l.x);
        wbuf[wv][m][1] = __expf(l.y);
        wbuf[wv][m][2] = __expf(l.z);
        wbuf[wv][m][3] = __expf(l.w);
    }
    // wave-synchronous: same wave wrote, same wave reads

    // ---- phase 2: channel accumulation (no dependent chain), bf16 h
    float accx = 0.f, accy = 0.f, dsum = 0.f;
    const int nst = m + 1;
    #pragma unroll 4
    for (int j = 0; j < nst; ++j) {
        const int   s = sbuf[wv][j];
        const float w = wbuf[wv][j][hh];
        dsum += w;
        const ushort2 hv = *(const ushort2*)(hb + (size_t)s * 128 + 2 * lane);
        accx += w * bf16f(hv.x);
        accy += w * bf16f(hv.y);
    }

    // ---- spill fallback (count is 0 for this data; correctness guard)
    int sc = *spill_cnt;
    if (sc > 0) {
        if (sc > SPILLCAP) sc = SPILLCAP;
        const float adh = aD[(size_t)n * 4 + hh];
        for (int q = 0; q < sc; ++q) {
            const int2 e = spill[q];
            if (e.y == nib) {
                const int s = e.x + base;
                float l = aS[(size_t)s * 4 + hh] + adh;
                l = (l > 0.f) ? l : NEG_SLOPE * l;
                const float w = __expf(l);
                dsum += w;
                const ushort2 hv = *(const ushort2*)(hb + (size_t)s * 128 + 2 * lane);
                accx += w * bf16f(hv.x);
                accy += w * bf16f(hv.y);
            }
        }
    }

    const float inv = 1.0f / (dsum + 1e-16f);
    const float2 bv = *(const float2*)(bias + 2 * lane);
    float2 o;
    o.x = accx * inv + bv.x;
    o.y = accy * inv + bv.y;
    *(float2*)(out + (size_t)n * 128 + 2 * lane) = o;
}

// ---------------------------------------------------------------------------
extern "C" void kernel_launch(void* const* d_in, const int* in_sizes, int n_in,
                              void* d_out, int out_size, void* d_ws, size_t ws_size,
                              hipStream_t stream) {
    const float* x    = (const float*)d_in[0];
    const int*   ei   = (const int*)  d_in[1];
    const float* W    = (const float*)d_in[2];
    const float* attS = (const float*)d_in[3];
    const float* attD = (const float*)d_in[4];
    const float* bias = (const float*)d_in[5];
    float* out = (float*)d_out;

    // workspace layout (4-byte units; base is 16B-aligned)
    float* ws = (float*)d_ws;
    unsigned short* hb  = (unsigned short*)ws;               // N*128 bf16 (8 MB)
    float* aS           = ws + (size_t)N_NODES * 64;         // N*4
    float* aD           = aS + (size_t)N_NODES * 4;          // N*4
    unsigned short* WtG = (unsigned short*)(aD + (size_t)N_NODES * 4);  // 128*128 bf16 (16B-aligned)
    int*   cnt          = (int*)(WtG + 128 * 128);           // T_LEN
    int*   spill_cnt    = cnt + T_LEN;                       // 1 (+1 pad)
    int*   ell          = spill_cnt + 2;                     // T_LEN*ELLCAP
    int2*  spill        = (int2*)(ell + T_LEN * ELLCAP);     // SPILLCAP int2

    // prep: zero cnt/spill_cnt + build bf16 W^T (replaces memset dispatch)
    prep_kernel<<<81, 256, 0, stream>>>(W, cnt, WtG);

    // fused: MFMA GEMM + logits (blocks 0..511) || ELL build (blocks 512..767)
    gemm_ell_kernel<<<GEMM_BLOCKS + 256, 256, 0, stream>>>(
        x, WtG, attS, attD, ei, hb, aS, aD, cnt, ell, spill_cnt, spill);

    // gather-aggregate with fused softmax-normalize + bias
    gather_kernel<<<N_NODES / 4, 256, 0, stream>>>(cnt, ell, spill_cnt, spill,
                                                   hb, aS, aD, bias, out);
}

// Round 12
// 42.621 us; speedup vs baseline: 2.2674x; 1.0033x over previous
//
#include <hip/hip_runtime.h>

#define BATCH    8
#define T_LEN    4096
#define D_DIM    128
#define H_HEADS  4
#define O_DIM    32
#define E_EDGES  65536
#define N_NODES  (BATCH * T_LEN)      // 32768
#define NEG_SLOPE 0.2f
#define ELLCAP   64
#define SPILLCAP 8192
#define GEMM_BLOCKS 512               // 64 rows each

typedef __attribute__((ext_vector_type(8))) short short8;
typedef __attribute__((ext_vector_type(4))) float f32x4;

// round-to-nearest-even fp32 -> bf16 bits
__device__ __forceinline__ unsigned int bf16b(float f) {
    unsigned int u = __float_as_uint(f);
    u += 0x7FFFu + ((u >> 16) & 1u);
    return u >> 16;
}
__device__ __forceinline__ unsigned int bf16pack(float lo, float hi) {
    return bf16b(lo) | (bf16b(hi) << 16);
}
__device__ __forceinline__ float bf16f(unsigned short u) {
    return __uint_as_float((unsigned int)u << 16);
}

// ---------------------------------------------------------------------------
// int64-vs-int32 layout detection (edge values < 4096 -> int64 odd words all 0)
// ---------------------------------------------------------------------------
__device__ __forceinline__ int detect_shift(const int* ei, int tidx, int* s_sh) {
    if (tidx < 64) {
        const int nz = (ei[2 * tidx + 1] != 0) ? 1 : 0;
        const unsigned long long b = __ballot(nz);
        if (tidx == 0) *s_sh = (b == 0ull) ? 1 : 0;
    }
    __syncthreads();
    return *s_sh;
}

// ---------------------------------------------------------------------------
// Prep: zero cnt[4096]+spill_cnt AND build global bf16 W^T (Wt[col][k]).
// ---------------------------------------------------------------------------
__launch_bounds__(256)
__global__ void prep_kernel(const float* __restrict__ W,
                            int* __restrict__ cnt,
                            unsigned short* __restrict__ WtG) {
    const int g = blockIdx.x * 256 + threadIdx.x;
    if (g < T_LEN + 1) cnt[g] = 0;                       // cnt + spill_cnt
    const int i = g - 4352;
    if (i >= 0 && i < 128 * 128) {
        const int k   = i >> 7;
        const int col = i & 127;                         // coalesced W read
        WtG[col * 128 + k] = (unsigned short)bf16b(W[k * 128 + col]);
    }
}

// ---------------------------------------------------------------------------
// Fused: blocks [0,512) = bf16-MFMA GEMM h=X*W + attention logits (64 rows
// per block, ~52 KB LDS -> 3 blocks/CU); blocks [512,768) = ELL build.
// MFMA fragment layout (m97-lineage, ref-checked): A[l&15][k0+(l>>4)*8+j],
// B = Wt[col l&15][same ks], D: row=(l>>4)*4+reg, col=l&15.
// h stored as bf16 (halves gather read traffic).
// ---------------------------------------------------------------------------
__launch_bounds__(256)
__global__ void gemm_ell_kernel(const float* __restrict__ x,
                                const unsigned short* __restrict__ WtG,
                                const float* __restrict__ attS,
                                const float* __restrict__ attD,
                                const int* __restrict__ ei,
                                unsigned short* __restrict__ hb,
                                float* __restrict__ aS,
                                float* __restrict__ aD,
                                int* __restrict__ cnt,
                                int* __restrict__ ell,
                                int* __restrict__ spill_cnt,
                                int2* __restrict__ spill) {
    __shared__ short Xb[64][136];    // rows x k, bf16 (stride 272 B)
    __shared__ short Wt[128][136];   // cols x k, bf16
    __shared__ int   s_sh;

    const int tid = threadIdx.x;

    if (blockIdx.x >= GEMM_BLOCKS) {
        // ---------------- ELL build branch ----------------
        const int sh = detect_shift(ei, tid, &s_sh);
        const int j  = (blockIdx.x - GEMM_BLOCKS) * 256 + tid;  // covers E_EDGES
        const int s  = ei[j << sh];
        const int d  = ei[(E_EDGES + j) << sh];
        const int p  = atomicAdd(&cnt[d], 1);
        if (p < ELLCAP) {
            ell[d * ELLCAP + p] = s;
        } else {
            const int q = atomicAdd(spill_cnt, 1);
            if (q < SPILLCAP) spill[q] = make_int2(s, d);
        }
        return;
    }

    // ---------------- GEMM branch ----------------
    // batch = blk%8 (XCD pin), 64-row tile = blk/8
    const int row0 = (blockIdx.x & 7) * T_LEN + ((blockIdx.x >> 3) << 6);

    // stage X tile (64x128 fp32 -> bf16), coalesced float4 reads
    const float4* X4 = (const float4*)(x + (size_t)row0 * 128);
    #pragma unroll
    for (int i = 0; i < 8; ++i) {
        const int idx = tid + 256 * i;
        const int row = idx >> 5;
        const int c4  = (idx & 31) * 4;
        const float4 v = X4[idx];
        uint2 u;
        u.x = bf16pack(v.x, v.y);
        u.y = bf16pack(v.z, v.w);
        *(uint2*)&Xb[row][c4] = u;
    }

    // stage Wt (already bf16+transposed in global), coalesced short8 loads
    #pragma unroll
    for (int i = 0; i < 8; ++i) {
        const int idx = tid + 256 * i;          // 2048 chunks of 8 shorts
        const int row = idx >> 4;
        const int off = (idx & 15) * 8;
        *(short8*)&Wt[row][off] = *(const short8*)&WtG[row * 128 + off];
    }
    __syncthreads();

    const int wv    = tid >> 6;        // wave 0..3 -> rows wv*16..+16
    const int l     = tid & 63;
    const int lr    = l & 15;
    const int lg    = l >> 4;
    const int wrow0 = wv * 16;

    f32x4 acc[8];
    #pragma unroll
    for (int cf = 0; cf < 8; ++cf) acc[cf] = (f32x4){0.f, 0.f, 0.f, 0.f};

    #pragma unroll
    for (int kt = 0; kt < 4; ++kt) {
        const int k0 = kt * 32 + lg * 8;
        const short8 a = *(const short8*)&Xb[wrow0 + lr][k0];
        #pragma unroll
        for (int cf = 0; cf < 8; ++cf) {
            const short8 b = *(const short8*)&Wt[cf * 16 + lr][k0];
            acc[cf] = __builtin_amdgcn_mfma_f32_16x16x32_bf16(a, b, acc[cf], 0, 0, 0);
        }
    }

    // store h as bf16: D row = (lg*4 + r), col = cf*16 + lr
    #pragma unroll
    for (int cf = 0; cf < 8; ++cf) {
        #pragma unroll
        for (int r = 0; r < 4; ++r) {
            const int row = row0 + wrow0 + lg * 4 + r;
            hb[(size_t)row * 128 + cf * 16 + lr] = (unsigned short)bf16b(acc[cf][r]);
        }
    }

    // fused attention logits (fp32 acc): aS[n][hd] = sum_c h[n][c]*attS[c]
    float psr[4][4];   // [r][head]
    float pdr[4][4];
    #pragma unroll
    for (int r = 0; r < 4; ++r)
        #pragma unroll
        for (int hd = 0; hd < 4; ++hd) { psr[r][hd] = 0.f; pdr[r][hd] = 0.f; }

    #pragma unroll
    for (int cf = 0; cf < 8; ++cf) {
        const float aSc = attS[cf * 16 + lr];
        const float aDc = attD[cf * 16 + lr];
        const int   hd  = cf >> 1;
        #pragma unroll
        for (int r = 0; r < 4; ++r) {
            psr[r][hd] += acc[cf][r] * aSc;
            pdr[r][hd] += acc[cf][r] * aDc;
        }
    }
    #pragma unroll
    for (int r = 0; r < 4; ++r)
        #pragma unroll
        for (int hd = 0; hd < 4; ++hd)
            #pragma unroll
            for (int off = 1; off < 16; off <<= 1) {
                psr[r][hd] += __shfl_xor(psr[r][hd], off);
                pdr[r][hd] += __shfl_xor(pdr[r][hd], off);
            }
    if (lr == 0) {
        #pragma unroll
        for (int r = 0; r < 4; ++r) {
            const int row = row0 + wrow0 + lg * 4 + r;
            *(float4*)&aS[(size_t)row * 4] =
                make_float4(psr[r][0], psr[r][1], psr[r][2], psr[r][3]);
            *(float4*)&aD[(size_t)row * 4] =
                make_float4(pdr[r][0], pdr[r][1], pdr[r][2], pdr[r][3]);
        }
    }
}

// ---------------------------------------------------------------------------
// Gather-aggregate v4: wave = one (batch,node).
// Phase 1: stage ELL col + w4 = exp(lrelu(aS4[s]+aD4[n])) into LDS.
// Phase 2: TWO h-rows per iteration — lanes 0-31 process even-j edges,
// lanes 32-63 odd-j edges; lane owns 4 channels (ushort4 load). Iteration
// count halves vs v3; cross-half shfl_xor(32) combines acc + dsum at the
// end. Spill fallback handled by half-0 lanes only (all 128 channels).
// ---------------------------------------------------------------------------
__launch_bounds__(256)
__global__ void gather_kernel(const int* __restrict__ cnt,
                              const int* __restrict__ ell,
                              const int* __restrict__ spill_cnt,
                              const int2* __restrict__ spill,
                              const unsigned short* __restrict__ hb,
                              const float* __restrict__ aS,
                              const float* __restrict__ aD,
                              const float* __restrict__ bias,
                              float* __restrict__ out) {
    __shared__ int   sbuf[4][ELLCAP + 1];
    __shared__ float wbuf[4][ELLCAP + 1][4];

    const int batch = blockIdx.x & 7;                 // XCD pin: batch slab in L2
    const int wv    = threadIdx.x >> 6;               // wave 0..3
    const int nib   = ((blockIdx.x >> 3) << 2) + wv;  // node within batch
    const int lane  = threadIdx.x & 63;
    const int base  = batch * T_LEN;
    const int n     = base + nib;

    const int deg = cnt[nib];
    const int m   = (deg < ELLCAP) ? deg : ELLCAP;    // staged edge count

    const float4 ad4 = *(const float4*)(aD + (size_t)n * 4);

    // ---- phase 1: stage edges (lane j -> slot j)
    if (lane < m) {
        const int s = ell[nib * ELLCAP + lane] + base;
        const float4 as4 = *(const float4*)(aS + (size_t)s * 4);
        float4 l;
        l.x = as4.x + ad4.x; l.x = (l.x > 0.f) ? l.x : NEG_SLOPE * l.x;
        l.y = as4.y + ad4.y; l.y = (l.y > 0.f) ? l.y : NEG_SLOPE * l.y;
        l.z = as4.z + ad4.z; l.z = (l.z > 0.f) ? l.z : NEG_SLOPE * l.z;
        l.w = as4.w + ad4.w; l.w = (l.w > 0.f) ? l.w : NEG_SLOPE * l.w;
        sbuf[wv][lane]    = s;
        wbuf[wv][lane][0] = __expf(l.x);
        wbuf[wv][lane][1] = __expf(l.y);
        wbuf[wv][lane][2] = __expf(l.z);
        wbuf[wv][lane][3] = __expf(l.w);
    }
    // self loop -> slot m (lane m for m<64; lane 0 doubles up when m==64)
    if (lane == (m & 63)) {
        const float4 as4 = *(const float4*)(aS + (size_t)n * 4);
        float4 l;
        l.x = as4.x + ad4.x; l.x = (l.x > 0.f) ? l.x : NEG_SLOPE * l.x;
        l.y = as4.y + ad4.y; l.y = (l.y > 0.f) ? l.y : NEG_SLOPE * l.y;
        l.z = as4.z + ad4.z; l.z = (l.z > 0.f) ? l.z : NEG_SLOPE * l.z;
        l.w = as4.w + ad4.w; l.w = (l.w > 0.f) ? l.w : NEG_SLOPE * l.w;
        sbuf[wv][m]    = n;
        wbuf[wv][m][0] = __expf(l.x);
        wbuf[wv][m][1] = __expf(l.y);
        wbuf[wv][m][2] = __expf(l.z);
        wbuf[wv][m][3] = __expf(l.w);
    }
    // wave-synchronous: same wave wrote, same wave reads

    // ---- phase 2: two edges per iteration (half = lane>>5 picks parity)
    const int half = lane >> 5;
    const int li   = lane & 31;
    const int ci   = li * 4;          // 4 owned channels
    const int hh   = li >> 3;         // head of those channels

    float4 A = make_float4(0.f, 0.f, 0.f, 0.f);
    float dsum = 0.f;
    const int nst = m + 1;
    #pragma unroll 4
    for (int j = half; j < nst; j += 2) {
        const int   s = sbuf[wv][j];
        const float w = wbuf[wv][j][hh];
        dsum += w;
        const ushort4 hv = *(const ushort4*)(hb + (size_t)s * 128 + ci);
        A.x += w * bf16f(hv.x);
        A.y += w * bf16f(hv.y);
        A.z += w * bf16f(hv.z);
        A.w += w * bf16f(hv.w);
    }

    // ---- spill fallback (half-0 lanes only; count is 0 for this data)
    int sc = *spill_cnt;
    if (sc > 0 && half == 0) {
        if (sc > SPILLCAP) sc = SPILLCAP;
        const float adh = aD[(size_t)n * 4 + hh];
        for (int q = 0; q < sc; ++q) {
            const int2 e = spill[q];
            if (e.y == nib) {
                const int s = e.x + base;
                float l = aS[(size_t)s * 4 + hh] + adh;
                l = (l > 0.f) ? l : NEG_SLOPE * l;
                const float w = __expf(l);
                dsum += w;
                const ushort4 hv = *(const ushort4*)(hb + (size_t)s * 128 + ci);
                A.x += w * bf16f(hv.x);
                A.y += w * bf16f(hv.y);
                A.z += w * bf16f(hv.z);
                A.w += w * bf16f(hv.w);
            }
        }
    }

    // combine the two halves (lanes l and l+32 hold the same channels)
    A.x += __shfl_xor(A.x, 32);
    A.y += __shfl_xor(A.y, 32);
    A.z += __shfl_xor(A.z, 32);
    A.w += __shfl_xor(A.w, 32);
    dsum += __shfl_xor(dsum, 32);

    if (half == 0) {
        const float inv = 1.0f / (dsum + 1e-16f);
        const float4 b = *(const float4*)(bias + ci);
        float4 o;
        o.x = A.x * inv + b.x;
        o.y = A.y * inv + b.y;
        o.z = A.z * inv + b.z;
        o.w = A.w * inv + b.w;
        *(float4*)(out + (size_t)n * 128 + ci) = o;
    }
}

// ---------------------------------------------------------------------------
extern "C" void kernel_launch(void* const* d_in, const int* in_sizes, int n_in,
                              void* d_out, int out_size, void* d_ws, size_t ws_size,
                              hipStream_t stream) {
    const float* x    = (const float*)d_in[0];
    const int*   ei   = (const int*)  d_in[1];
    const float* W    = (const float*)d_in[2];
    const float* attS = (const float*)d_in[3];
    const float* attD = (const float*)d_in[4];
    const float* bias = (const float*)d_in[5];
    float* out = (float*)d_out;

    // workspace layout (4-byte units; base is 16B-aligned)
    float* ws = (float*)d_ws;
    unsigned short* hb  = (unsigned short*)ws;               // N*128 bf16 (8 MB)
    float* aS           = ws + (size_t)N_NODES * 64;         // N*4
    float* aD           = aS + (size_t)N_NODES * 4;          // N*4
    unsigned short* WtG = (unsigned short*)(aD + (size_t)N_NODES * 4);  // 128*128 bf16
    int*   cnt          = (int*)(WtG + 128 * 128);           // T_LEN
    int*   spill_cnt    = cnt + T_LEN;                       // 1 (+1 pad)
    int*   ell          = spill_cnt + 2;                     // T_LEN*ELLCAP
    int2*  spill        = (int2*)(ell + T_LEN * ELLCAP);     // SPILLCAP int2

    // prep: zero cnt/spill_cnt + build bf16 W^T
    prep_kernel<<<81, 256, 0, stream>>>(W, cnt, WtG);

    // fused: MFMA GEMM + logits (blocks 0..511) || ELL build (blocks 512..767)
    gemm_ell_kernel<<<GEMM_BLOCKS + 256, 256, 0, stream>>>(
        x, WtG, attS, attD, ei, hb, aS, aD, cnt, ell, spill_cnt, spill);

    // gather-aggregate with fused softmax-normalize + bias
    gather_kernel<<<N_NODES / 4, 256, 0, stream>>>(cnt, ell, spill_cnt, spill,
                                                   hb, aS, aD, bias, out);
}

// Round 13
// 40.809 us; speedup vs baseline: 2.3681x; 1.0444x over previous
//
#include <hip/hip_runtime.h>

#define BATCH    8
#define T_LEN    4096
#define D_DIM    128
#define H_HEADS  4
#define O_DIM    32
#define E_EDGES  65536
#define N_NODES  (BATCH * T_LEN)      // 32768
#define NEG_SLOPE 0.2f
#define ELLCAP   64
#define SPILLCAP 8192
#define GEMM_BLOCKS 512               // 64 rows each

typedef __attribute__((ext_vector_type(8))) short short8;
typedef __attribute__((ext_vector_type(4))) float f32x4;

// round-to-nearest-even fp32 -> bf16 bits
__device__ __forceinline__ unsigned int bf16b(float f) {
    unsigned int u = __float_as_uint(f);
    u += 0x7FFFu + ((u >> 16) & 1u);
    return u >> 16;
}
__device__ __forceinline__ unsigned int bf16pack(float lo, float hi) {
    return bf16b(lo) | (bf16b(hi) << 16);
}
__device__ __forceinline__ float bf16f(unsigned short u) {
    return __uint_as_float((unsigned int)u << 16);
}

// ---------------------------------------------------------------------------
// int64-vs-int32 layout detection (edge values < 4096 -> int64 odd words all 0)
// ---------------------------------------------------------------------------
__device__ __forceinline__ int detect_shift(const int* ei, int tidx, int* s_sh) {
    if (tidx < 64) {
        const int nz = (ei[2 * tidx + 1] != 0) ? 1 : 0;
        const unsigned long long b = __ballot(nz);
        if (tidx == 0) *s_sh = (b == 0ull) ? 1 : 0;
    }
    __syncthreads();
    return *s_sh;
}

// ---------------------------------------------------------------------------
// Prep: zero cnt[4096]+spill_cnt AND build global bf16 W^T (Wt[col][k]).
// ---------------------------------------------------------------------------
__launch_bounds__(256)
__global__ void prep_kernel(const float* __restrict__ W,
                            int* __restrict__ cnt,
                            unsigned short* __restrict__ WtG) {
    const int g = blockIdx.x * 256 + threadIdx.x;
    if (g < T_LEN + 1) cnt[g] = 0;                       // cnt + spill_cnt
    const int i = g - 4352;
    if (i >= 0 && i < 128 * 128) {
        const int k   = i >> 7;
        const int col = i & 127;                         // coalesced W read
        WtG[col * 128 + k] = (unsigned short)bf16b(W[k * 128 + col]);
    }
}

// ---------------------------------------------------------------------------
// Fused: blocks [0,512) = bf16-MFMA GEMM h=X*W + attention logits (64 rows
// per block, ~52 KB LDS -> 3 blocks/CU); blocks [512,768) = ELL build.
// MFMA fragment layout (m97-lineage, ref-checked): A[l&15][k0+(l>>4)*8+j],
// B = Wt[col l&15][same ks], D: row=(l>>4)*4+reg, col=l&15.
// h stored as bf16 (halves gather read traffic).
// ---------------------------------------------------------------------------
__launch_bounds__(256)
__global__ void gemm_ell_kernel(const float* __restrict__ x,
                                const unsigned short* __restrict__ WtG,
                                const float* __restrict__ attS,
                                const float* __restrict__ attD,
                                const int* __restrict__ ei,
                                unsigned short* __restrict__ hb,
                                float* __restrict__ aS,
                                float* __restrict__ aD,
                                int* __restrict__ cnt,
                                int* __restrict__ ell,
                                int* __restrict__ spill_cnt,
                                int2* __restrict__ spill) {
    __shared__ short Xb[64][136];    // rows x k, bf16 (stride 272 B)
    __shared__ short Wt[128][136];   // cols x k, bf16
    __shared__ int   s_sh;

    const int tid = threadIdx.x;

    if (blockIdx.x >= GEMM_BLOCKS) {
        // ---------------- ELL build branch ----------------
        const int sh = detect_shift(ei, tid, &s_sh);
        const int j  = (blockIdx.x - GEMM_BLOCKS) * 256 + tid;  // covers E_EDGES
        const int s  = ei[j << sh];
        const int d  = ei[(E_EDGES + j) << sh];
        const int p  = atomicAdd(&cnt[d], 1);
        if (p < ELLCAP) {
            ell[d * ELLCAP + p] = s;
        } else {
            const int q = atomicAdd(spill_cnt, 1);
            if (q < SPILLCAP) spill[q] = make_int2(s, d);
        }
        return;
    }

    // ---------------- GEMM branch ----------------
    // batch = blk%8 (XCD pin), 64-row tile = blk/8
    const int row0 = (blockIdx.x & 7) * T_LEN + ((blockIdx.x >> 3) << 6);

    // stage X tile (64x128 fp32 -> bf16), coalesced float4 reads
    const float4* X4 = (const float4*)(x + (size_t)row0 * 128);
    #pragma unroll
    for (int i = 0; i < 8; ++i) {
        const int idx = tid + 256 * i;
        const int row = idx >> 5;
        const int c4  = (idx & 31) * 4;
        const float4 v = X4[idx];
        uint2 u;
        u.x = bf16pack(v.x, v.y);
        u.y = bf16pack(v.z, v.w);
        *(uint2*)&Xb[row][c4] = u;
    }

    // stage Wt (already bf16+transposed in global), coalesced short8 loads
    #pragma unroll
    for (int i = 0; i < 8; ++i) {
        const int idx = tid + 256 * i;          // 2048 chunks of 8 shorts
        const int row = idx >> 4;
        const int off = (idx & 15) * 8;
        *(short8*)&Wt[row][off] = *(const short8*)&WtG[row * 128 + off];
    }
    __syncthreads();

    const int wv    = tid >> 6;        // wave 0..3 -> rows wv*16..+16
    const int l     = tid & 63;
    const int lr    = l & 15;
    const int lg    = l >> 4;
    const int wrow0 = wv * 16;

    f32x4 acc[8];
    #pragma unroll
    for (int cf = 0; cf < 8; ++cf) acc[cf] = (f32x4){0.f, 0.f, 0.f, 0.f};

    #pragma unroll
    for (int kt = 0; kt < 4; ++kt) {
        const int k0 = kt * 32 + lg * 8;
        const short8 a = *(const short8*)&Xb[wrow0 + lr][k0];
        #pragma unroll
        for (int cf = 0; cf < 8; ++cf) {
            const short8 b = *(const short8*)&Wt[cf * 16 + lr][k0];
            acc[cf] = __builtin_amdgcn_mfma_f32_16x16x32_bf16(a, b, acc[cf], 0, 0, 0);
        }
    }

    // store h as bf16: D row = (lg*4 + r), col = cf*16 + lr
    #pragma unroll
    for (int cf = 0; cf < 8; ++cf) {
        #pragma unroll
        for (int r = 0; r < 4; ++r) {
            const int row = row0 + wrow0 + lg * 4 + r;
            hb[(size_t)row * 128 + cf * 16 + lr] = (unsigned short)bf16b(acc[cf][r]);
        }
    }

    // fused attention logits (fp32 acc): aS[n][hd] = sum_c h[n][c]*attS[c]
    float psr[4][4];   // [r][head]
    float pdr[4][4];
    #pragma unroll
    for (int r = 0; r < 4; ++r)
        #pragma unroll
        for (int hd = 0; hd < 4; ++hd) { psr[r][hd] = 0.f; pdr[r][hd] = 0.f; }

    #pragma unroll
    for (int cf = 0; cf < 8; ++cf) {
        const float aSc = attS[cf * 16 + lr];
        const float aDc = attD[cf * 16 + lr];
        const int   hd  = cf >> 1;
        #pragma unroll
        for (int r = 0; r < 4; ++r) {
            psr[r][hd] += acc[cf][r] * aSc;
            pdr[r][hd] += acc[cf][r] * aDc;
        }
    }
    #pragma unroll
    for (int r = 0; r < 4; ++r)
        #pragma unroll
        for (int hd = 0; hd < 4; ++hd)
            #pragma unroll
            for (int off = 1; off < 16; off <<= 1) {
                psr[r][hd] += __shfl_xor(psr[r][hd], off);
                pdr[r][hd] += __shfl_xor(pdr[r][hd], off);
            }
    if (lr == 0) {
        #pragma unroll
        for (int r = 0; r < 4; ++r) {
            const int row = row0 + wrow0 + lg * 4 + r;
            *(float4*)&aS[(size_t)row * 4] =
                make_float4(psr[r][0], psr[r][1], psr[r][2], psr[r][3]);
            *(float4*)&aD[(size_t)row * 4] =
                make_float4(pdr[r][0], pdr[r][1], pdr[r][2], pdr[r][3]);
        }
    }
}

// ---------------------------------------------------------------------------
// Gather-aggregate v5: TWO nodes per wave (lanes 0-31 = node A = even,
// lanes 32-63 = node B = odd). Phase 1: self-loop at slot 0 (lane 0 of each
// half) + ELL edge li at slot li+1 (34+ active lanes/wave vs 17 in v3/v4).
// Phase 2: each half runs its own dependence-free channel loop (lane owns 4
// channels, ushort4 h loads); NO cross-lane reduction at all. 1024-thread
// blocks (32 nodes each), 1024 blocks, ~75 KB LDS -> 2 blocks/CU (full
// 32-wave occupancy). XCD batch pinning via blk%8. Zero atomics.
// ---------------------------------------------------------------------------
__launch_bounds__(1024)
__global__ void gather_kernel(const int* __restrict__ cnt,
                              const int* __restrict__ ell,
                              const int* __restrict__ spill_cnt,
                              const int2* __restrict__ spill,
                              const unsigned short* __restrict__ hb,
                              const float* __restrict__ aS,
                              const float* __restrict__ aD,
                              const float* __restrict__ bias,
                              float* __restrict__ out) {
    __shared__ int   sbuf[16][2][ELLCAP + 1];
    __shared__ float wbuf[16][2][ELLCAP + 1][4];

    const int batch = blockIdx.x & 7;                 // XCD pin: batch slab in L2
    const int wv    = threadIdx.x >> 6;               // wave 0..15
    const int lane  = threadIdx.x & 63;
    const int half  = lane >> 5;                      // 0 = node A, 1 = node B
    const int li    = lane & 31;
    const int base  = batch * T_LEN;
    const int nib   = ((blockIdx.x >> 3) << 5) + (wv << 1) + half;  // node in batch
    const int n     = base + nib;

    const int deg = cnt[nib];
    const int m   = (deg < ELLCAP) ? deg : ELLCAP;    // staged edge count

    const float4 ad4 = *(const float4*)(aD + (size_t)n * 4);

    // ---- phase 1: self loop -> slot 0 (lane 0 of each half)
    if (li == 0) {
        const float4 as4 = *(const float4*)(aS + (size_t)n * 4);
        float4 l;
        l.x = as4.x + ad4.x; l.x = (l.x > 0.f) ? l.x : NEG_SLOPE * l.x;
        l.y = as4.y + ad4.y; l.y = (l.y > 0.f) ? l.y : NEG_SLOPE * l.y;
        l.z = as4.z + ad4.z; l.z = (l.z > 0.f) ? l.z : NEG_SLOPE * l.z;
        l.w = as4.w + ad4.w; l.w = (l.w > 0.f) ? l.w : NEG_SLOPE * l.w;
        sbuf[wv][half][0]    = n;
        wbuf[wv][half][0][0] = __expf(l.x);
        wbuf[wv][half][0][1] = __expf(l.y);
        wbuf[wv][half][0][2] = __expf(l.z);
        wbuf[wv][half][0][3] = __expf(l.w);
    }
    // ELL edge li -> slot li+1 (plus rare second pass for deg>32)
    for (int jj = li; jj < m; jj += 32) {
        const int s = ell[nib * ELLCAP + jj] + base;
        const float4 as4 = *(const float4*)(aS + (size_t)s * 4);
        float4 l;
        l.x = as4.x + ad4.x; l.x = (l.x > 0.f) ? l.x : NEG_SLOPE * l.x;
        l.y = as4.y + ad4.y; l.y = (l.y > 0.f) ? l.y : NEG_SLOPE * l.y;
        l.z = as4.z + ad4.z; l.z = (l.z > 0.f) ? l.z : NEG_SLOPE * l.z;
        l.w = as4.w + ad4.w; l.w = (l.w > 0.f) ? l.w : NEG_SLOPE * l.w;
        sbuf[wv][half][jj + 1]    = s;
        wbuf[wv][half][jj + 1][0] = __expf(l.x);
        wbuf[wv][half][jj + 1][1] = __expf(l.y);
        wbuf[wv][half][jj + 1][2] = __expf(l.z);
        wbuf[wv][half][jj + 1][3] = __expf(l.w);
    }
    // wave-synchronous: same wave wrote, same wave reads (DS ops in order)

    // ---- phase 2: each half accumulates its own node (no dependent chain)
    const int ci = li * 4;            // 4 owned channels
    const int hh = li >> 3;           // head of those channels

    float4 A = make_float4(0.f, 0.f, 0.f, 0.f);
    float dsum = 0.f;
    const int nst = m + 1;
    #pragma unroll 4
    for (int j = 0; j < nst; ++j) {
        const int   s = sbuf[wv][half][j];
        const float w = wbuf[wv][half][j][hh];
        dsum += w;
        const ushort4 hv = *(const ushort4*)(hb + (size_t)s * 128 + ci);
        A.x += w * bf16f(hv.x);
        A.y += w * bf16f(hv.y);
        A.z += w * bf16f(hv.z);
        A.w += w * bf16f(hv.w);
    }

    // ---- spill fallback (per half; count is 0 for this data)
    int sc = *spill_cnt;
    if (sc > 0) {
        if (sc > SPILLCAP) sc = SPILLCAP;
        const float adh = (hh == 0) ? ad4.x : (hh == 1) ? ad4.y
                        : (hh == 2) ? ad4.z : ad4.w;
        for (int q = 0; q < sc; ++q) {
            const int2 e = spill[q];
            if (e.y == nib) {
                const int s = e.x + base;
                float l = aS[(size_t)s * 4 + hh] + adh;
                l = (l > 0.f) ? l : NEG_SLOPE * l;
                const float w = __expf(l);
                dsum += w;
                const ushort4 hv = *(const ushort4*)(hb + (size_t)s * 128 + ci);
                A.x += w * bf16f(hv.x);
                A.y += w * bf16f(hv.y);
                A.z += w * bf16f(hv.z);
                A.w += w * bf16f(hv.w);
            }
        }
    }

    // finalize + write (all 64 lanes; wave covers node pair = 1 KB contiguous)
    const float inv = 1.0f / (dsum + 1e-16f);
    const float4 b = *(const float4*)(bias + ci);
    float4 o;
    o.x = A.x * inv + b.x;
    o.y = A.y * inv + b.y;
    o.z = A.z * inv + b.z;
    o.w = A.w * inv + b.w;
    *(float4*)(out + (size_t)n * 128 + ci) = o;
}

// ---------------------------------------------------------------------------
extern "C" void kernel_launch(void* const* d_in, const int* in_sizes, int n_in,
                              void* d_out, int out_size, void* d_ws, size_t ws_size,
                              hipStream_t stream) {
    const float* x    = (const float*)d_in[0];
    const int*   ei   = (const int*)  d_in[1];
    const float* W    = (const float*)d_in[2];
    const float* attS = (const float*)d_in[3];
    const float* attD = (const float*)d_in[4];
    const float* bias = (const float*)d_in[5];
    float* out = (float*)d_out;

    // workspace layout (4-byte units; base is 16B-aligned)
    float* ws = (float*)d_ws;
    unsigned short* hb  = (unsigned short*)ws;               // N*128 bf16 (8 MB)
    float* aS           = ws + (size_t)N_NODES * 64;         // N*4
    float* aD           = aS + (size_t)N_NODES * 4;          // N*4
    unsigned short* WtG = (unsigned short*)(aD + (size_t)N_NODES * 4);  // 128*128 bf16
    int*   cnt          = (int*)(WtG + 128 * 128);           // T_LEN
    int*   spill_cnt    = cnt + T_LEN;                       // 1 (+1 pad)
    int*   ell          = spill_cnt + 2;                     // T_LEN*ELLCAP
    int2*  spill        = (int2*)(ell + T_LEN * ELLCAP);     // SPILLCAP int2

    // prep: zero cnt/spill_cnt + build bf16 W^T
    prep_kernel<<<81, 256, 0, stream>>>(W, cnt, WtG);

    // fused: MFMA GEMM + logits (blocks 0..511) || ELL build (blocks 512..767)
    gemm_ell_kernel<<<GEMM_BLOCKS + 256, 256, 0, stream>>>(
        x, WtG, attS, attD, ei, hb, aS, aD, cnt, ell, spill_cnt, spill);

    // gather-aggregate v5: 2 nodes/wave, 1024-thread blocks
    gather_kernel<<<N_NODES / 32, 1024, 0, stream>>>(cnt, ell, spill_cnt, spill,
                                                     hb, aS, aD, bias, out);
}